// Round 2
// 4672.590 us; speedup vs baseline: 2.2136x; 2.2136x over previous
//
#include <hip/hip_runtime.h>
#include <hip/hip_bf16.h>

#define HID 2048
#define FFN_DIM 7168
#define NE 8
#define NT 8192            // tokens = B*S
#define NR 16384           // rows = NT * TOP_K
#define BK 32

typedef __bf16 bf16_t;
using bf16x8 = __attribute__((ext_vector_type(8))) __bf16;
using bf16x4 = __attribute__((ext_vector_type(4))) __bf16;
using floatx4 = __attribute__((ext_vector_type(4))) float;

typedef __attribute__((address_space(3))) unsigned int lds_u32_t;
typedef const __attribute__((address_space(1))) unsigned int glb_u32_t;

// ---- workspace layout (bytes) ----
#define OFF_CNT    0        // 8 ints (zeroed by memset)
#define OFF_EOFF   128      // 9 ints
#define OFF_CURSOR 256      // 8 ints
#define OFF_SELE   1024                     // int[NR]
#define OFF_SELW   (OFF_SELE + NR * 4)      // float[NR]
#define OFF_RTOK   (OFF_SELW + NR * 4)      // int[NR]
#define OFF_RW     (OFF_RTOK + NR * 4)      // float[NR]
#define OFF_REXP   (OFF_RW + NR * 4)        // int[NR]
#define OFF_A      331776                   // bf16[NR][HID]
#define OFF_HMID   (OFF_A + (size_t)NR * HID * 2)  // bf16[NR][FFN]

// ---------------- router: logits, top-2, counts ----------------
__global__ __launch_bounds__(64) void router_kernel(
    const float* __restrict__ x, const float* __restrict__ gw,
    float* __restrict__ logits_out, int* __restrict__ cnt,
    int* __restrict__ sel_e, float* __restrict__ sel_w)
{
    int t = blockIdx.x;
    int lane = threadIdx.x;
    const float* xr = x + (size_t)t * HID;
    float acc[NE];
#pragma unroll
    for (int e = 0; e < NE; e++) acc[e] = 0.f;
    for (int h = lane; h < HID; h += 64) {
        float xv = xr[h];
#pragma unroll
        for (int e = 0; e < NE; e++) acc[e] += xv * gw[e * HID + h];
    }
#pragma unroll
    for (int e = 0; e < NE; e++) {
#pragma unroll
        for (int off = 32; off > 0; off >>= 1)
            acc[e] += __shfl_down(acc[e], off);
    }
    if (lane == 0) {
#pragma unroll
        for (int e = 0; e < NE; e++) logits_out[t * NE + e] = acc[e];
        int i0 = 0;
#pragma unroll
        for (int e = 1; e < NE; e++) if (acc[e] > acc[i0]) i0 = e;
        int i1 = (i0 == 0) ? 1 : 0;
#pragma unroll
        for (int e = 0; e < NE; e++) if (e != i0 && acc[e] > acc[i1]) i1 = e;
        float w0 = 1.f / (1.f + __expf(acc[i1] - acc[i0]));
        float w1 = 1.f - w0;
        sel_e[t * 2] = i0; sel_e[t * 2 + 1] = i1;
        sel_w[t * 2] = w0; sel_w[t * 2 + 1] = w1;
        atomicAdd(&cnt[i0], 1);
        atomicAdd(&cnt[i1], 1);
    }
}

__global__ void offsets_kernel(const int* __restrict__ cnt,
                               int* __restrict__ eoff, int* __restrict__ cursor)
{
    int s = 0;
    for (int e = 0; e < NE; e++) { eoff[e] = s; cursor[e] = s; s += cnt[e]; }
    eoff[NE] = s;
}

__global__ __launch_bounds__(256) void scatter_kernel(
    const int* __restrict__ sel_e, const float* __restrict__ sel_w,
    int* __restrict__ cursor, int* __restrict__ rtok,
    float* __restrict__ rw, int* __restrict__ rexp)
{
    int i = blockIdx.x * 256 + threadIdx.x;
    if (i >= NR) return;
    int t = i >> 1;
    int e = sel_e[i];
    float w = sel_w[i];
    int pos = atomicAdd(&cursor[e], 1);
    rtok[pos] = t; rw[pos] = w; rexp[pos] = e;
}

// ---------------- gather: A_all[r][h] = bf16(x[t][h] / scales[e][h]) ----------------
__global__ __launch_bounds__(256) void gather_kernel(
    const float* __restrict__ x, const float* __restrict__ scales,
    const int* __restrict__ rtok, const int* __restrict__ rexp,
    bf16_t* __restrict__ A)
{
    int r = blockIdx.x;
    int t = rtok[r];
    int e = rexp[r];
    const float* xr = x + (size_t)t * HID;
    const float* sr = scales + (size_t)e * HID;
    bf16_t* ar = A + (size_t)r * HID;
    for (int h = threadIdx.x * 4; h < HID; h += 256 * 4) {
        float4 xv = *(const float4*)&xr[h];
        float4 sv = *(const float4*)&sr[h];
        bf16x4 v = { (bf16_t)(xv.x / sv.x), (bf16_t)(xv.y / sv.y),
                     (bf16_t)(xv.z / sv.z), (bf16_t)(xv.w / sv.w) };
        *(bf16x4*)&ar[h] = v;
    }
}

// ---------------- unified 128x128 MFMA GEMM template ----------------
// A: bf16 [rows][KDIM] rows partitioned per-expert via eoff; staged via global_load_lds.
// B: fp32 [e][NTILES*128][KDIM]; reg-staged with fp32->bf16 convert (issue-early/write-late).
// MODE 0: hmid[gr][f]  = bf16(acc)                       (gemm1 pass a: s1 = A@w1^T)
// MODE 1: hmid[gr][f]  = bf16(silu(hmid[gr][f]) * acc)   (gemm1 pass b: s3 = A@w3^T)
// MODE 2: out[tok][h] += rw[gr] * acc  (atomic)           (gemm2: hmid@w2^T)
template<int KDIM, int NTILES, int MODE>
__global__ __launch_bounds__(256, 3) void moe_gemm_kernel(
    const bf16_t* __restrict__ Abase, const float* __restrict__ Bbase,
    const int* __restrict__ eoff, bf16_t* __restrict__ hmid,
    const int* __restrict__ rtok, const float* __restrict__ rwt,
    float* __restrict__ out)
{
    // bijective XCD-chunk swizzle: grid = 32*NTILES*8, %8==0.
    // Each XCD gets one expert's contiguous mt-fastest range -> B panel read ~once/XCD.
    constexpr int NWG = 32 * NTILES * NE;
    constexpr int CPX = NWG / 8;
    int bid = blockIdx.x;
    int lid = (bid & 7) * CPX + (bid >> 3);
    int mt = lid & 31;
    int nt = (lid >> 5) % NTILES;
    int e  = lid / (32 * NTILES);

    int row0 = eoff[e], row_end = eoff[e + 1];
    int row_base = row0 + mt * 128;
    if (row_base >= row_end) return;
    int n_base = nt * 128;

    __shared__ bf16_t As[2][128 * BK];   // 8 KB each
    __shared__ bf16_t Bs[2][128 * BK];   // 8 KB each  -> 32 KB total

    int tid = threadIdx.x;
    int lane = tid & 63;
    int wv = tid >> 6;
    int wm = wv & 1, wn = wv >> 1;

    const float* Be = Bbase + (size_t)e * KDIM * (NTILES * 128);

    floatx4 acc[4][4];
#pragma unroll
    for (int i = 0; i < 4; i++)
#pragma unroll
        for (int j = 0; j < 4; j++) acc[i][j] = (floatx4){0.f, 0.f, 0.f, 0.f};

    // --- A staging (global_load_lds, 16B/lane, linear LDS): wave wv covers rows wv*32..+31
    const bf16_t* aptr[2];
#pragma unroll
    for (int i = 0; i < 2; i++) {
        int gr = row_base + wv * 32 + i * 16 + (lane >> 2);
        if (gr >= row_end) gr = row_end - 1;   // clamp: garbage rows masked at epilogue
        aptr[i] = Abase + (size_t)gr * KDIM + (lane & 3) * 8;
    }
    auto stageA = [&](int buf, int k0) {
#pragma unroll
        for (int i = 0; i < 2; i++) {
            __builtin_amdgcn_global_load_lds(
                (glb_u32_t*)(aptr[i] + k0),
                (lds_u32_t*)&As[buf][(wv * 32 + i * 16) * BK],
                16, 0, 0);
        }
    };

    // --- B staging mapping: thread -> (row srow, 16-float half koff)
    int srow = tid >> 1;
    int koff = (tid & 1) * 16;
    const float* bsrc = Be + (size_t)(n_base + srow) * KDIM + koff;

    // prologue: tile 0 -> buffer 0
    stageA(0, 0);
    {
        float4 b0 = *(const float4*)(bsrc),     b1 = *(const float4*)(bsrc + 4);
        float4 b2 = *(const float4*)(bsrc + 8), b3 = *(const float4*)(bsrc + 12);
        bf16x8 p0 = { (bf16_t)b0.x, (bf16_t)b0.y, (bf16_t)b0.z, (bf16_t)b0.w,
                      (bf16_t)b1.x, (bf16_t)b1.y, (bf16_t)b1.z, (bf16_t)b1.w };
        bf16x8 p1 = { (bf16_t)b2.x, (bf16_t)b2.y, (bf16_t)b2.z, (bf16_t)b2.w,
                      (bf16_t)b3.x, (bf16_t)b3.y, (bf16_t)b3.z, (bf16_t)b3.w };
        *(bf16x8*)&Bs[0][srow * BK + koff] = p0;
        *(bf16x8*)&Bs[0][srow * BK + koff + 8] = p1;
    }
    __syncthreads();

    constexpr int KSTEPS = KDIM / BK;
    for (int kt = 0; kt < KSTEPS; ++kt) {
        int cur = kt & 1;
        bool pf = (kt + 1 < KSTEPS);
        float4 b0, b1, b2, b3;
        if (pf) {
            int k0n = (kt + 1) * BK;
            stageA(cur ^ 1, k0n);                 // async -> As[nxt]
            const float* s = bsrc + k0n;          // issue-early, consumed post-MFMA
            b0 = *(const float4*)(s);      b1 = *(const float4*)(s + 4);
            b2 = *(const float4*)(s + 8);  b3 = *(const float4*)(s + 12);
        }

        // compute on buffer cur
        int kq = (lane >> 4) * 8;
        bf16x8 bfr[4];
#pragma unroll
        for (int in = 0; in < 4; in++)
            bfr[in] = *(const bf16x8*)&Bs[cur][(wn * 64 + in * 16 + (lane & 15)) * BK + kq];
#pragma unroll
        for (int im = 0; im < 4; im++) {
            bf16x8 a = *(const bf16x8*)&As[cur][(wm * 64 + im * 16 + (lane & 15)) * BK + kq];
#pragma unroll
            for (int in = 0; in < 4; in++)
                acc[im][in] = __builtin_amdgcn_mfma_f32_16x16x32_bf16(a, bfr[in], acc[im][in], 0, 0, 0);
        }

        if (pf) {   // write-late into nxt buffer
            bf16x8 p0 = { (bf16_t)b0.x, (bf16_t)b0.y, (bf16_t)b0.z, (bf16_t)b0.w,
                          (bf16_t)b1.x, (bf16_t)b1.y, (bf16_t)b1.z, (bf16_t)b1.w };
            bf16x8 p1 = { (bf16_t)b2.x, (bf16_t)b2.y, (bf16_t)b2.z, (bf16_t)b2.w,
                          (bf16_t)b3.x, (bf16_t)b3.y, (bf16_t)b3.z, (bf16_t)b3.w };
            *(bf16x8*)&Bs[cur ^ 1][srow * BK + koff] = p0;
            *(bf16x8*)&Bs[cur ^ 1][srow * BK + koff + 8] = p1;
        }
        __syncthreads();   // single drain point per k-step (covers global_load_lds too)
    }

    // epilogue
#pragma unroll
    for (int im = 0; im < 4; im++) {
#pragma unroll
        for (int r = 0; r < 4; r++) {
            int m = wm * 64 + im * 16 + (lane >> 4) * 4 + r;
            int gr = row_base + m;
            if (gr < row_end) {
                if (MODE == 0) {
#pragma unroll
                    for (int in = 0; in < 4; in++) {
                        int f = n_base + wn * 64 + in * 16 + (lane & 15);
                        hmid[(size_t)gr * FFN_DIM + f] = (bf16_t)acc[im][in][r];
                    }
                } else if (MODE == 1) {
#pragma unroll
                    for (int in = 0; in < 4; in++) {
                        int f = n_base + wn * 64 + in * 16 + (lane & 15);
                        float s1 = (float)hmid[(size_t)gr * FFN_DIM + f];
                        float hm = s1 / (1.f + __expf(-s1)) * acc[im][in][r];
                        hmid[(size_t)gr * FFN_DIM + f] = (bf16_t)hm;
                    }
                } else {
                    int tkn = rtok[gr];
                    float wgt = rwt[gr];
#pragma unroll
                    for (int in = 0; in < 4; in++) {
                        int h = n_base + wn * 64 + in * 16 + (lane & 15);
                        atomicAdd(&out[(size_t)tkn * HID + h], wgt * acc[im][in][r]);
                    }
                }
            }
        }
    }
}

extern "C" void kernel_launch(void* const* d_in, const int* in_sizes, int n_in,
                              void* d_out, int out_size, void* d_ws, size_t ws_size,
                              hipStream_t stream)
{
    const float* x      = (const float*)d_in[0];
    const float* gw     = (const float*)d_in[1];
    const float* w1     = (const float*)d_in[2];
    const float* w3     = (const float*)d_in[3];
    const float* w2     = (const float*)d_in[4];
    const float* scales = (const float*)d_in[5];
    float* out = (float*)d_out;
    float* logits = out + (size_t)NT * HID;

    char* ws = (char*)d_ws;
    int*    cnt    = (int*)(ws + OFF_CNT);
    int*    eoff   = (int*)(ws + OFF_EOFF);
    int*    cursor = (int*)(ws + OFF_CURSOR);
    int*    sel_e  = (int*)(ws + OFF_SELE);
    float*  sel_w  = (float*)(ws + OFF_SELW);
    int*    rtok   = (int*)(ws + OFF_RTOK);
    float*  rwt    = (float*)(ws + OFF_RW);
    int*    rexp   = (int*)(ws + OFF_REXP);
    bf16_t* Abuf   = (bf16_t*)(ws + OFF_A);
    bf16_t* hmid   = (bf16_t*)(ws + OFF_HMID);

    hipMemsetAsync(d_out, 0, (size_t)NT * HID * sizeof(float), stream);
    hipMemsetAsync(ws, 0, 1024, stream);

    router_kernel<<<NT, 64, 0, stream>>>(x, gw, logits, cnt, sel_e, sel_w);
    offsets_kernel<<<1, 1, 0, stream>>>(cnt, eoff, cursor);
    scatter_kernel<<<NR / 256, 256, 0, stream>>>(sel_e, sel_w, cursor, rtok, rwt, rexp);
    gather_kernel<<<NR, 256, 0, stream>>>(x, scales, rtok, rexp, Abuf);

    // gemm1 pass a: s1 = A @ w1^T  -> hmid (raw, bf16)
    moe_gemm_kernel<HID, 56, 0><<<32 * 56 * NE, 256, 0, stream>>>(
        Abuf, w1, eoff, hmid, nullptr, nullptr, nullptr);
    // gemm1 pass b: hmid = silu(s1) * (A @ w3^T)
    moe_gemm_kernel<HID, 56, 1><<<32 * 56 * NE, 256, 0, stream>>>(
        Abuf, w3, eoff, hmid, nullptr, nullptr, nullptr);
    // gemm2: out[tok] += w_r * (hmid @ w2^T)
    moe_gemm_kernel<FFN_DIM, 16, 2><<<32 * 16 * NE, 256, 0, stream>>>(
        hmid, w2, eoff, rtok ? hmid : hmid, rtok, rwt, out);
}